// Round 2
// baseline (788.990 us; speedup 1.0000x reference)
//
#include <hip/hip_runtime.h>

#define NN     50000
#define NE     200000
#define ETOT   250000   // NE + NN self-loops
#define FIN    165
#define KP1    192      // FIN padded to mult of 32
#define HEADS  8
#define CH     100
#define DIM    800      // 8*100
#define MPAD   50048    // 391*128
#define NP1    896      // 7*128  (pad of 800)
#define DIM2   1600     // W2|Wres1 fused output
#define NP2    1664     // 13*128 (pad of 1600)
#define NEG    0.2f

typedef unsigned short u16;
typedef unsigned int   u32;
typedef __bf16 bf16x8 __attribute__((ext_vector_type(8)));
typedef float  f32x4  __attribute__((ext_vector_type(4)));

__device__ __forceinline__ u16 f2b(float f) {
  u32 u = __float_as_uint(f);
  u = (u + 0x7FFFu + ((u >> 16) & 1u)) >> 16;   // RNE
  return (u16)u;
}
__device__ __forceinline__ float b2f(u16 u) { return __uint_as_float(((u32)u) << 16); }

// ---------------- CSR build (dst -> list of src), reused by all 3 layers ----------------
__global__ void k_count(const int* __restrict__ ei, int* __restrict__ cnt) {
  int e = blockIdx.x * 256 + threadIdx.x;
  if (e >= ETOT) return;
  int d = (e < NE) ? ei[NE + e] : (e - NE);
  atomicAdd(&cnt[d], 1);
}
__global__ void k_bsum(const int* __restrict__ cnt, int* __restrict__ bs) {
  __shared__ int sm[256];
  int i = blockIdx.x * 256 + threadIdx.x;
  sm[threadIdx.x] = (i < NN) ? cnt[i] : 0;
  __syncthreads();
  for (int off = 128; off; off >>= 1) {
    if (threadIdx.x < off) sm[threadIdx.x] += sm[threadIdx.x + off];
    __syncthreads();
  }
  if (!threadIdx.x) bs[blockIdx.x] = sm[0];
}
__global__ void k_top(int* __restrict__ bs, int* __restrict__ rs, int nb) {
  __shared__ int sm[256];
  int t = threadIdx.x;
  int v = (t < nb) ? bs[t] : 0;
  sm[t] = v; __syncthreads();
  for (int off = 1; off < 256; off <<= 1) {
    int add = (t >= off) ? sm[t - off] : 0;
    __syncthreads();
    sm[t] += add;
    __syncthreads();
  }
  if (t < nb) bs[t] = sm[t] - v;   // exclusive block offsets
  if (!t) rs[NN] = ETOT;
}
__global__ void k_scan(const int* __restrict__ cnt, const int* __restrict__ bs, int* __restrict__ rs) {
  __shared__ int sm[256];
  int t = threadIdx.x, i = blockIdx.x * 256 + t;
  int v = (i < NN) ? cnt[i] : 0;
  sm[t] = v; __syncthreads();
  for (int off = 1; off < 256; off <<= 1) {
    int add = (t >= off) ? sm[t - off] : 0;
    __syncthreads();
    sm[t] += add;
    __syncthreads();
  }
  if (i < NN) rs[i] = bs[blockIdx.x] + sm[t] - v;
}
__global__ void k_fill(const int* __restrict__ ei, const int* __restrict__ rs,
                       int* __restrict__ cur, int* __restrict__ esrc) {
  int e = blockIdx.x * 256 + threadIdx.x;
  if (e >= ETOT) return;
  int s, d;
  if (e < NE) { s = ei[e]; d = ei[NE + e]; } else { s = d = e - NE; }
  int pos = atomicAdd(&cur[d], 1);
  esrc[rs[d] + pos] = s;
}

// ---------------- converts (fp32 -> bf16, pad, transpose weights) ----------------
__global__ void k_cvt_x(const float* __restrict__ x, u16* __restrict__ A) {
  int idx = blockIdx.x * 256 + threadIdx.x;   // MPAD*KP1 exact
  int r = idx / KP1, k = idx - r * KP1;
  float v = (r < NN && k < FIN) ? x[r * FIN + k] : 0.f;
  A[idx] = f2b(v);
}
__global__ void k_cvt_w1(const float* __restrict__ W1, u16* __restrict__ Bt) {
  int idx = blockIdx.x * 256 + threadIdx.x;   // NP1*KP1 exact
  int j = idx / KP1, k = idx - j * KP1;
  float v = (j < DIM && k < FIN) ? W1[k * DIM + j] : 0.f;
  Bt[idx] = f2b(v);
}
__global__ void k_cvt_w2(const float* __restrict__ W2, const float* __restrict__ Wr1,
                         u16* __restrict__ Bt) {
  int idx = blockIdx.x * 256 + threadIdx.x;   // NP2*DIM exact
  int j = idx / DIM, k = idx - j * DIM;
  float v = 0.f;
  if (j < DIM) v = W2[k * DIM + j];
  else if (j < 2 * DIM) v = Wr1[k * DIM + (j - DIM)];
  Bt[idx] = f2b(v);
}

// ---------------- bf16 MFMA GEMM: C[M][ldC] = A[M][K] * Bt[Npad][K]^T ----------------
// grid.x = N-tiles (fast-varying) so consecutive blocks share the same A-panel:
// A is fetched ~once from HBM instead of once per N-tile (L2/L3 reuse).
__device__ __forceinline__ void gl_lds16(const u16* g, u16* l) {
  __builtin_amdgcn_global_load_lds((const __attribute__((address_space(1))) void*)g,
                                   (__attribute__((address_space(3))) void*)l, 16, 0, 0);
}

__global__ __launch_bounds__(256) void k_gemm(const u16* __restrict__ A, const u16* __restrict__ Bt,
                                              u16* __restrict__ C, int ksteps, int K,
                                              int Nreal, int ldC) {
  __shared__ __align__(16) u16 lA[128 * 32];
  __shared__ __align__(16) u16 lB[128 * 32];
  int t = threadIdx.x;
  int lane = t & 63, wv = t >> 6;
  int tn = blockIdx.x * 128, tm = blockIdx.y * 128;   // swapped: N fastest
  int wr = (wv >> 1) * 64, wc = (wv & 1) * 64;
  int rl = lane & 15, kl = (lane >> 4) * 8;
  f32x4 acc[4][4];
#pragma unroll
  for (int i = 0; i < 4; ++i)
#pragma unroll
    for (int j = 0; j < 4; ++j) acc[i][j] = (f32x4){0.f, 0.f, 0.f, 0.f};

  for (int ks = 0; ks < ksteps; ++ks) {
    int k0 = ks * 32;
    __syncthreads();
#pragma unroll
    for (int r = 0; r < 2; ++r) {
      int chunk = r * 256 + t;               // 512 chunks x 16B = 128x32 bf16 tile
      int row = chunk >> 2, cb = (chunk & 3) * 8;
      gl_lds16(A + (size_t)(tm + row) * K + k0 + cb, &lA[chunk * 8]);
      gl_lds16(Bt + (size_t)(tn + row) * K + k0 + cb, &lB[chunk * 8]);
    }
    __syncthreads();
    bf16x8 af[4], bfr[4];
#pragma unroll
    for (int i = 0; i < 4; ++i) {
      af[i]  = *(const bf16x8*)&lA[(wr + i * 16 + rl) * 32 + kl];
      bfr[i] = *(const bf16x8*)&lB[(wc + i * 16 + rl) * 32 + kl];
    }
#pragma unroll
    for (int i = 0; i < 4; ++i)
#pragma unroll
      for (int j = 0; j < 4; ++j)
        acc[i][j] = __builtin_amdgcn_mfma_f32_16x16x32_bf16(af[i], bfr[j], acc[i][j], 0, 0, 0);
  }
  int rq = (lane >> 4) * 4;
#pragma unroll
  for (int i = 0; i < 4; ++i) {
#pragma unroll
    for (int j = 0; j < 4; ++j) {
      int col = tn + wc + j * 16 + rl;
      if (col < Nreal) {
#pragma unroll
        for (int q = 0; q < 4; ++q) {
          int row = tm + wr + i * 16 + rq + q;
          C[(size_t)row * ldC + col] = f2b(acc[i][j][q]);
        }
      }
    }
  }
}

// ---------------- per-(node,head) attention scalars ----------------
__global__ void k_esed(const u16* __restrict__ Hp, int ld, const float* __restrict__ as,
                       const float* __restrict__ ad, float* __restrict__ es, float* __restrict__ ed) {
  int idx = blockIdx.x * 256 + threadIdx.x;
  if (idx >= NN * HEADS) return;
  int n = idx >> 3, h = idx & 7;
  const ushort4* r4 = (const ushort4*)(Hp + (size_t)n * ld + h * CH);
  const float4* a4 = (const float4*)(as + h * CH);
  const float4* d4 = (const float4*)(ad + h * CH);
  float se = 0.f, de = 0.f;
#pragma unroll
  for (int i = 0; i < CH / 4; ++i) {
    ushort4 u = r4[i];
    float4 a = a4[i], d = d4[i];
    float v0 = b2f(u.x), v1 = b2f(u.y), v2 = b2f(u.z), v3 = b2f(u.w);
    se += v0 * a.x + v1 * a.y + v2 * a.z + v3 * a.w;
    de += v0 * d.x + v1 * d.y + v2 * d.z + v3 * d.w;
  }
  es[idx] = se; ed[idx] = de;
}

// ---- fused softmax-stats + weighted aggregation + bias (+residual) + ELU -> bf16 ----
// threads 0..7 compute per-head (max, 1/denom) over incoming edges; then 200
// threads each handle 4 contiguous channels (one head each: 100 % 4 == 0) with
// ushort4 loads and a single exp per edge.
template <int LAYER>
__global__ __launch_bounds__(256) void k_agg(const int* __restrict__ rs, const int* __restrict__ esrc,
    const u16* __restrict__ Hp, const float* __restrict__ es, const float* __restrict__ ed,
    const float* __restrict__ bias, const u16* __restrict__ resid, u16* __restrict__ out) {
  const int ld = (LAYER == 2) ? DIM2 : DIM;
  __shared__ float sm[16];   // [0..7]=max, [8..15]=1/denom
  int n = blockIdx.x, t = threadIdx.x;
  int beg = rs[n], end = rs[n + 1];
  if (t < 8) {
    float edv = ed[n * 8 + t];
    float m = -3e38f;
    for (int j = beg; j < end; ++j) {
      float x = es[esrc[j] * 8 + t] + edv;
      x = x > 0.f ? x : NEG * x;
      m = fmaxf(m, x);
    }
    float den = 0.f;
    for (int j = beg; j < end; ++j) {
      float x = es[esrc[j] * 8 + t] + edv;
      x = x > 0.f ? x : NEG * x;
      den += __expf(x - m);
    }
    sm[t] = m; sm[8 + t] = 1.f / (den + 1e-16f);
  }
  __syncthreads();
  if (t >= 200) return;
  int c = t * 4;
  int h = t / 25;
  float edv = ed[n * 8 + h];
  float m = sm[h], inv = sm[8 + h];
  float a0 = 0.f, a1 = 0.f, a2 = 0.f, a3 = 0.f;
  for (int j = beg; j < end; ++j) {
    int s = esrc[j];
    float x = es[s * 8 + h] + edv;
    x = x > 0.f ? x : NEG * x;
    float w = __expf(x - m) * inv;
    ushort4 u = *(const ushort4*)(Hp + (size_t)s * ld + c);
    a0 += w * b2f(u.x); a1 += w * b2f(u.y); a2 += w * b2f(u.z); a3 += w * b2f(u.w);
  }
  const float4 bb = *(const float4*)(bias + c);
  float v0 = a0 + bb.x, v1 = a1 + bb.y, v2 = a2 + bb.z, v3 = a3 + bb.w;
  if (LAYER == 2) {
    ushort4 r = *(const ushort4*)(resid + (size_t)n * DIM2 + c);
    v0 += b2f(r.x); v1 += b2f(r.y); v2 += b2f(r.z); v3 += b2f(r.w);
  }
  v0 = v0 > 0.f ? v0 : __expf(v0) - 1.f;
  v1 = v1 > 0.f ? v1 : __expf(v1) - 1.f;
  v2 = v2 > 0.f ? v2 : __expf(v2) - 1.f;
  v3 = v3 > 0.f ? v3 : __expf(v3) - 1.f;
  ushort4 o;
  o.x = f2b(v0); o.y = f2b(v1); o.z = f2b(v2); o.w = f2b(v3);
  *(ushort4*)(out + (size_t)n * DIM + c) = o;
}

// ---------------- layer 3: skinny projections, one wave per node ----------------
__global__ __launch_bounds__(256) void k_l3(const u16* __restrict__ h2, const float* __restrict__ x,
    const float* __restrict__ W3, const float* __restrict__ Wres2, const float* __restrict__ Wskip,
    const float* __restrict__ a3s, const float* __restrict__ a3d, const float* __restrict__ b3,
    float* __restrict__ H3p, float* __restrict__ base, float* __restrict__ es3, float* __restrict__ ed3) {
  int wv = threadIdx.x >> 6, lane = threadIdx.x & 63;
  int n = blockIdx.x * 4 + wv;
  if (n >= NN) return;
  float p0 = 0.f, p1 = 0.f, r0 = 0.f, r1 = 0.f;
  const u16* hr = h2 + (size_t)n * DIM;
  for (int c = lane; c < DIM; c += 64) {
    float v = b2f(hr[c]);
    p0 += v * W3[2 * c];    p1 += v * W3[2 * c + 1];
    r0 += v * Wres2[2 * c]; r1 += v * Wres2[2 * c + 1];
  }
  float s0 = 0.f, s1 = 0.f;
  const float* xr = x + (size_t)n * FIN;
  for (int c = lane; c < FIN; c += 64) {
    float v = xr[c];
    s0 += v * Wskip[2 * c]; s1 += v * Wskip[2 * c + 1];
  }
#pragma unroll
  for (int off = 32; off; off >>= 1) {
    p0 += __shfl_down(p0, off); p1 += __shfl_down(p1, off);
    r0 += __shfl_down(r0, off); r1 += __shfl_down(r1, off);
    s0 += __shfl_down(s0, off); s1 += __shfl_down(s1, off);
  }
  if (!lane) {
    H3p[2 * n] = p0; H3p[2 * n + 1] = p1;
    es3[n] = p0 * a3s[0] + p1 * a3s[1];
    ed3[n] = p0 * a3d[0] + p1 * a3d[1];
    base[2 * n]     = r0 + s0 + b3[0];
    base[2 * n + 1] = r1 + s1 + b3[1];
  }
}

// ---------------- layer 3 softmax+aggregate (1 head, 2 ch) -> final logits ----------------
__global__ void k_l3agg(const int* __restrict__ rs, const int* __restrict__ esrc,
                        const float* __restrict__ H3p, const float* __restrict__ base,
                        const float* __restrict__ es3, const float* __restrict__ ed3,
                        float* __restrict__ out) {
  int n = blockIdx.x * 256 + threadIdx.x;
  if (n >= NN) return;
  int beg = rs[n], end = rs[n + 1];
  float edv = ed3[n];
  float m = -3e38f;
  for (int j = beg; j < end; ++j) {
    float e = es3[esrc[j]] + edv;
    e = e > 0.f ? e : NEG * e;
    m = fmaxf(m, e);
  }
  float den = 0.f, a0 = 0.f, a1 = 0.f;
  for (int j = beg; j < end; ++j) {
    int s = esrc[j];
    float e = es3[s] + edv;
    e = e > 0.f ? e : NEG * e;
    float ex = __expf(e - m);
    den += ex;
    a0 += ex * H3p[2 * s];
    a1 += ex * H3p[2 * s + 1];
  }
  float inv = 1.f / (den + 1e-16f);
  out[2 * n]     = base[2 * n]     + a0 * inv;
  out[2 * n + 1] = base[2 * n + 1] + a1 * inv;
}

extern "C" void kernel_launch(void* const* d_in, const int* in_sizes, int n_in,
                              void* d_out, int out_size, void* d_ws, size_t ws_size,
                              hipStream_t stream) {
  (void)in_sizes; (void)n_in; (void)out_size; (void)ws_size;
  const float* x    = (const float*)d_in[0];
  const int*   ei   = (const int*)d_in[1];
  const float* W1   = (const float*)d_in[2];
  const float* a1s  = (const float*)d_in[3];
  const float* a1d  = (const float*)d_in[4];
  const float* b1   = (const float*)d_in[5];
  const float* W2   = (const float*)d_in[6];
  const float* a2s  = (const float*)d_in[7];
  const float* a2d  = (const float*)d_in[8];
  const float* b2   = (const float*)d_in[9];
  const float* W3   = (const float*)d_in[10];
  const float* a3s  = (const float*)d_in[11];
  const float* a3d  = (const float*)d_in[12];
  const float* b3   = (const float*)d_in[13];
  const float* Wr1  = (const float*)d_in[14];
  const float* Wr2  = (const float*)d_in[15];
  const float* Wsk  = (const float*)d_in[16];
  float* out = (float*)d_out;

  char* w = (char*)d_ws;
  size_t off = 0;
  auto alloc = [&](size_t bytes) { void* p = w + off; off += (bytes + 255) & ~(size_t)255; return p; };
  int* cnt   = (int*)alloc((size_t)NN * 4);
  int* cur   = (int*)alloc((size_t)NN * 4);
  int* rs    = (int*)alloc((size_t)(NN + 1) * 4);
  int* bs    = (int*)alloc(256 * 4);
  int* esrc  = (int*)alloc((size_t)ETOT * 4);
  float* es  = (float*)alloc((size_t)NN * HEADS * 4);
  float* ed  = (float*)alloc((size_t)NN * HEADS * 4);
  u16* W1t   = (u16*)alloc((size_t)NP1 * KP1 * 2);
  u16* W2t   = (u16*)alloc((size_t)NP2 * DIM * 2);
  float* H3p = (float*)alloc((size_t)NN * 2 * 4);
  float* base= (float*)alloc((size_t)NN * 2 * 4);
  float* es3 = (float*)alloc((size_t)NN * 4);
  float* ed3 = (float*)alloc((size_t)NN * 4);
  u16* bufB  = (u16*)alloc((size_t)MPAD * DIM * 2);    // h1bf, later h2bf
  u16* bufA  = (u16*)alloc((size_t)MPAD * DIM2 * 2);   // H1p, later G2 (fused proj|resid)
  u16* H1p   = bufA;
  u16* G2    = bufA;
  u16* A1    = bufA + (size_t)MPAD * DIM;              // alias upper half of bufA (dead before G2)

  const int nb = (NN + 255) / 256;        // 196
  const int ge = (ETOT + 255) / 256;      // 977
  const int gh = (NN * HEADS + 255) / 256;// 1563

  // CSR build
  hipMemsetAsync(cnt, 0, (size_t)NN * 4, stream);
  hipMemsetAsync(cur, 0, (size_t)NN * 4, stream);
  k_count<<<ge, 256, 0, stream>>>(ei, cnt);
  k_bsum <<<nb, 256, 0, stream>>>(cnt, bs);
  k_top  <<<1, 256, 0, stream>>>(bs, rs, nb);
  k_scan <<<nb, 256, 0, stream>>>(cnt, bs, rs);
  k_fill <<<ge, 256, 0, stream>>>(ei, rs, cur, esrc);

  // converts
  k_cvt_x <<<(MPAD * KP1) / 256, 256, 0, stream>>>(x, A1);
  k_cvt_w1<<<(NP1 * KP1) / 256, 256, 0, stream>>>(W1, W1t);
  k_cvt_w2<<<(NP2 * DIM) / 256, 256, 0, stream>>>(W2, Wr1, W2t);

  // layer 1
  k_gemm<<<dim3(NP1 / 128, MPAD / 128), 256, 0, stream>>>(A1, W1t, H1p, KP1 / 32, KP1, DIM, DIM);
  k_esed <<<gh, 256, 0, stream>>>(H1p, DIM, a1s, a1d, es, ed);
  k_agg<1><<<NN, 256, 0, stream>>>(rs, esrc, H1p, es, ed, b1, (const u16*)nullptr, bufB);

  // layer 2 (W2 and Wres1 fused into one GEMM: cols [0,800)=proj, [800,1600)=residual)
  k_gemm<<<dim3(NP2 / 128, MPAD / 128), 256, 0, stream>>>(bufB, W2t, G2, DIM / 32, DIM, DIM2, DIM2);
  k_esed <<<gh, 256, 0, stream>>>(G2, DIM2, a2s, a2d, es, ed);
  k_agg<2><<<NN, 256, 0, stream>>>(rs, esrc, G2, es, ed, b2, G2 + DIM, bufB);

  // layer 3
  k_l3   <<<(NN + 3) / 4, 256, 0, stream>>>(bufB, x, W3, Wr2, Wsk, a3s, a3d, b3, H3p, base, es3, ed3);
  k_l3agg<<<nb, 256, 0, stream>>>(rs, esrc, H3p, base, es3, ed3, out);
}

// Round 3
// 642.269 us; speedup vs baseline: 1.2284x; 1.2284x over previous
//
#include <hip/hip_runtime.h>

#define NN     50000
#define NE     200000
#define ETOT   250000   // NE + NN self-loops
#define FIN    165
#define KP1    192      // FIN padded to mult of 32
#define HEADS  8
#define CH     100
#define DIM    800      // 8*100
#define MPAD   50048    // 391*128
#define NP1    896      // 7*128  (pad of 800)
#define DIM2   1600     // W2|Wres1 fused output
#define NP2    1664     // 13*128 (pad of 1600)
#define NEG    0.2f

typedef unsigned short u16;
typedef unsigned int   u32;
typedef __bf16 bf16x8 __attribute__((ext_vector_type(8)));
typedef float  f32x4  __attribute__((ext_vector_type(4)));

__device__ __forceinline__ u16 f2b(float f) {
  u32 u = __float_as_uint(f);
  u = (u + 0x7FFFu + ((u >> 16) & 1u)) >> 16;   // RNE
  return (u16)u;
}
__device__ __forceinline__ float b2f(u16 u) { return __uint_as_float(((u32)u) << 16); }

// ---------------- CSR build (dst -> list of src), reused by all 3 layers ----------------
__global__ void k_count(const int* __restrict__ ei, int* __restrict__ cnt) {
  int e = blockIdx.x * 256 + threadIdx.x;
  if (e >= ETOT) return;
  int d = (e < NE) ? ei[NE + e] : (e - NE);
  atomicAdd(&cnt[d], 1);
}
__global__ void k_bsum(const int* __restrict__ cnt, int* __restrict__ bs) {
  __shared__ int sm[256];
  int i = blockIdx.x * 256 + threadIdx.x;
  sm[threadIdx.x] = (i < NN) ? cnt[i] : 0;
  __syncthreads();
  for (int off = 128; off; off >>= 1) {
    if (threadIdx.x < off) sm[threadIdx.x] += sm[threadIdx.x + off];
    __syncthreads();
  }
  if (!threadIdx.x) bs[blockIdx.x] = sm[0];
}
__global__ void k_top(int* __restrict__ bs, int* __restrict__ rs, int nb) {
  __shared__ int sm[256];
  int t = threadIdx.x;
  int v = (t < nb) ? bs[t] : 0;
  sm[t] = v; __syncthreads();
  for (int off = 1; off < 256; off <<= 1) {
    int add = (t >= off) ? sm[t - off] : 0;
    __syncthreads();
    sm[t] += add;
    __syncthreads();
  }
  if (t < nb) bs[t] = sm[t] - v;   // exclusive block offsets
  if (!t) rs[NN] = ETOT;
}
__global__ void k_scan(const int* __restrict__ cnt, const int* __restrict__ bs, int* __restrict__ rs) {
  __shared__ int sm[256];
  int t = threadIdx.x, i = blockIdx.x * 256 + t;
  int v = (i < NN) ? cnt[i] : 0;
  sm[t] = v; __syncthreads();
  for (int off = 1; off < 256; off <<= 1) {
    int add = (t >= off) ? sm[t - off] : 0;
    __syncthreads();
    sm[t] += add;
    __syncthreads();
  }
  if (i < NN) rs[i] = bs[blockIdx.x] + sm[t] - v;
}
__global__ void k_fill(const int* __restrict__ ei, const int* __restrict__ rs,
                       int* __restrict__ cur, int* __restrict__ esrc) {
  int e = blockIdx.x * 256 + threadIdx.x;
  if (e >= ETOT) return;
  int s, d;
  if (e < NE) { s = ei[e]; d = ei[NE + e]; } else { s = d = e - NE; }
  int pos = atomicAdd(&cur[d], 1);
  esrc[rs[d] + pos] = s;
}

// ---------------- converts (fp32 -> bf16, pad, transpose weights) ----------------
__global__ void k_cvt_x(const float* __restrict__ x, u16* __restrict__ A) {
  int idx = blockIdx.x * 256 + threadIdx.x;   // MPAD*KP1 exact
  int r = idx / KP1, k = idx - r * KP1;
  float v = (r < NN && k < FIN) ? x[r * FIN + k] : 0.f;
  A[idx] = f2b(v);
}
__global__ void k_cvt_w1(const float* __restrict__ W1, u16* __restrict__ Bt) {
  int idx = blockIdx.x * 256 + threadIdx.x;   // NP1*KP1 exact
  int j = idx / KP1, k = idx - j * KP1;
  float v = (j < DIM && k < FIN) ? W1[k * DIM + j] : 0.f;
  Bt[idx] = f2b(v);
}
__global__ void k_cvt_w2(const float* __restrict__ W2, const float* __restrict__ Wr1,
                         u16* __restrict__ Bt) {
  int idx = blockIdx.x * 256 + threadIdx.x;   // NP2*DIM exact
  int j = idx / DIM, k = idx - j * DIM;
  float v = 0.f;
  if (j < DIM) v = W2[k * DIM + j];
  else if (j < 2 * DIM) v = Wr1[k * DIM + (j - DIM)];
  Bt[idx] = f2b(v);
}

// ---------------- bf16 MFMA GEMM: C[M][ldC] = A[M][K] * Bt[Npad][K]^T ----------------
// T1: bijective XCD-chunked block swizzle (m204) so one XCD owns consecutive
//     (m,n) tiles -> A-panel reuse in that XCD's L2.
// T2: st-style XOR swizzle, both-sides: global SOURCE column-block permuted by
//     cbi ^= (row>>2)&3 (LDS dest stays linear for global_load_lds), READ applies
//     the same XOR -> quarter-wave's 16 rows spread over all 8 bank groups
//     (8-way conflict -> 2-way, free per m136).
__device__ __forceinline__ void gl_lds16(const u16* g, u16* l) {
  __builtin_amdgcn_global_load_lds((const __attribute__((address_space(1))) void*)g,
                                   (__attribute__((address_space(3))) void*)l, 16, 0, 0);
}

__global__ __launch_bounds__(256) void k_gemm(const u16* __restrict__ A, const u16* __restrict__ Bt,
                                              u16* __restrict__ C, int ksteps, int K,
                                              int Nreal, int ldC) {
  __shared__ __align__(16) u16 lA[128 * 32];
  __shared__ __align__(16) u16 lB[128 * 32];
  int t = threadIdx.x;
  int lane = t & 63, wv = t >> 6;

  // T1 XCD swizzle (hardware id -> logical tile id, bijective chunked)
  int nwg = gridDim.x * gridDim.y;
  int h = blockIdx.y * gridDim.x + blockIdx.x;
  int q = nwg >> 3, r8 = nwg & 7;
  int xcd = h & 7, i8 = h >> 3;
  int ln = (xcd < r8 ? xcd * (q + 1) : r8 * (q + 1) + (xcd - r8) * q) + i8;
  int tn = (ln % gridDim.x) * 128, tm = (ln / gridDim.x) * 128;

  int wr = (wv >> 1) * 64, wc = (wv & 1) * 64;
  int rl = lane & 15, kl = (lane >> 4) * 8;
  int swx = (rl & 12) << 1;                 // T2 read-side XOR (u16 units)
  f32x4 acc[4][4];
#pragma unroll
  for (int i = 0; i < 4; ++i)
#pragma unroll
    for (int j = 0; j < 4; ++j) acc[i][j] = (f32x4){0.f, 0.f, 0.f, 0.f};

  for (int ks = 0; ks < ksteps; ++ks) {
    int k0 = ks * 32;
    __syncthreads();
#pragma unroll
    for (int r = 0; r < 2; ++r) {
      int chunk = r * 256 + t;               // 512 chunks x 16B = 128x32 bf16 tile
      int row = chunk >> 2;
      int cbi = (chunk & 3) ^ ((row >> 2) & 3);   // T2 source-side permute
      gl_lds16(A + (size_t)(tm + row) * K + k0 + cbi * 8, &lA[chunk * 8]);
      gl_lds16(Bt + (size_t)(tn + row) * K + k0 + cbi * 8, &lB[chunk * 8]);
    }
    __syncthreads();
    bf16x8 af[4], bfr[4];
#pragma unroll
    for (int i = 0; i < 4; ++i) {
      af[i]  = *(const bf16x8*)&lA[(wr + i * 16 + rl) * 32 + (kl ^ swx)];
      bfr[i] = *(const bf16x8*)&lB[(wc + i * 16 + rl) * 32 + (kl ^ swx)];
    }
#pragma unroll
    for (int i = 0; i < 4; ++i)
#pragma unroll
      for (int j = 0; j < 4; ++j)
        acc[i][j] = __builtin_amdgcn_mfma_f32_16x16x32_bf16(af[i], bfr[j], acc[i][j], 0, 0, 0);
  }
  int rq = (lane >> 4) * 4;
#pragma unroll
  for (int i = 0; i < 4; ++i) {
#pragma unroll
    for (int j = 0; j < 4; ++j) {
      int col = tn + wc + j * 16 + rl;
      if (col < Nreal) {
#pragma unroll
        for (int q2 = 0; q2 < 4; ++q2) {
          int row = tm + wr + i * 16 + rq + q2;
          C[(size_t)row * ldC + col] = f2b(acc[i][j][q2]);
        }
      }
    }
  }
}

// ---------------- per-(node,head) attention scalars ----------------
__global__ void k_esed(const u16* __restrict__ Hp, int ld, const float* __restrict__ as,
                       const float* __restrict__ ad, float* __restrict__ es, float* __restrict__ ed) {
  int idx = blockIdx.x * 256 + threadIdx.x;
  if (idx >= NN * HEADS) return;
  int n = idx >> 3, h = idx & 7;
  const ushort4* r4 = (const ushort4*)(Hp + (size_t)n * ld + h * CH);
  const float4* a4 = (const float4*)(as + h * CH);
  const float4* d4 = (const float4*)(ad + h * CH);
  float se = 0.f, de = 0.f;
#pragma unroll
  for (int i = 0; i < CH / 4; ++i) {
    ushort4 u = r4[i];
    float4 a = a4[i], d = d4[i];
    float v0 = b2f(u.x), v1 = b2f(u.y), v2 = b2f(u.z), v3 = b2f(u.w);
    se += v0 * a.x + v1 * a.y + v2 * a.z + v3 * a.w;
    de += v0 * d.x + v1 * d.y + v2 * d.z + v3 * d.w;
  }
  es[idx] = se; ed[idx] = de;
}

// ---------------- per-(node,head) softmax stats; stores per-edge exp values ----------------
__global__ void k_stats(const int* __restrict__ rs, const int* __restrict__ esrc,
                        const float* __restrict__ es, const float* __restrict__ ed,
                        float* __restrict__ ex, float* __restrict__ dv) {
  int idx = blockIdx.x * 256 + threadIdx.x;
  if (idx >= NN * HEADS) return;
  int n = idx >> 3, h = idx & 7;
  int beg = rs[n], end = rs[n + 1];
  float edv = ed[idx];
  float m = -3e38f;
  for (int j = beg; j < end; ++j) {
    float x = es[esrc[j] * 8 + h] + edv;
    x = x > 0.f ? x : NEG * x;
    m = fmaxf(m, x);
  }
  float den = 0.f;
  for (int j = beg; j < end; ++j) {
    float x = es[esrc[j] * 8 + h] + edv;
    x = x > 0.f ? x : NEG * x;
    float e = __expf(x - m);
    ex[j * 8 + h] = e;
    den += e;
  }
  dv[idx] = 1.f / (den + 1e-16f);
}

// ---- aggregation: hot loop is ex-broadcast + ushort4 gather + FMA only ----
// 200 threads x 4 contiguous channels; 1/denom applied once after the loop.
template <int LAYER>
__global__ __launch_bounds__(256) void k_agg(const int* __restrict__ rs, const int* __restrict__ esrc,
    const u16* __restrict__ Hp, const float* __restrict__ ex, const float* __restrict__ dv,
    const float* __restrict__ bias, const u16* __restrict__ resid, u16* __restrict__ out) {
  const int ld = (LAYER == 2) ? DIM2 : DIM;
  int n = blockIdx.x, t = threadIdx.x;
  if (t >= 200) return;
  int beg = rs[n], end = rs[n + 1];
  int c = t * 4;
  int h = t / 25;
  float inv = dv[n * 8 + h];
  float a0 = 0.f, a1 = 0.f, a2 = 0.f, a3 = 0.f;
  for (int j = beg; j < end; ++j) {
    int s = esrc[j];
    float w = ex[j * 8 + h];
    ushort4 u = *(const ushort4*)(Hp + (size_t)s * ld + c);
    a0 += w * b2f(u.x); a1 += w * b2f(u.y); a2 += w * b2f(u.z); a3 += w * b2f(u.w);
  }
  const float4 bb = *(const float4*)(bias + c);
  float v0 = a0 * inv + bb.x, v1 = a1 * inv + bb.y, v2 = a2 * inv + bb.z, v3 = a3 * inv + bb.w;
  if (LAYER == 2) {
    ushort4 r = *(const ushort4*)(resid + (size_t)n * DIM2 + c);
    v0 += b2f(r.x); v1 += b2f(r.y); v2 += b2f(r.z); v3 += b2f(r.w);
  }
  v0 = v0 > 0.f ? v0 : __expf(v0) - 1.f;
  v1 = v1 > 0.f ? v1 : __expf(v1) - 1.f;
  v2 = v2 > 0.f ? v2 : __expf(v2) - 1.f;
  v3 = v3 > 0.f ? v3 : __expf(v3) - 1.f;
  ushort4 o;
  o.x = f2b(v0); o.y = f2b(v1); o.z = f2b(v2); o.w = f2b(v3);
  *(ushort4*)(out + (size_t)n * DIM + c) = o;
}

// ---------------- layer 3: skinny projections, one wave per node ----------------
__global__ __launch_bounds__(256) void k_l3(const u16* __restrict__ h2, const float* __restrict__ x,
    const float* __restrict__ W3, const float* __restrict__ Wres2, const float* __restrict__ Wskip,
    const float* __restrict__ a3s, const float* __restrict__ a3d, const float* __restrict__ b3,
    float* __restrict__ H3p, float* __restrict__ base, float* __restrict__ es3, float* __restrict__ ed3) {
  int wv = threadIdx.x >> 6, lane = threadIdx.x & 63;
  int n = blockIdx.x * 4 + wv;
  if (n >= NN) return;
  float p0 = 0.f, p1 = 0.f, r0 = 0.f, r1 = 0.f;
  const u16* hr = h2 + (size_t)n * DIM;
  for (int c = lane; c < DIM; c += 64) {
    float v = b2f(hr[c]);
    p0 += v * W3[2 * c];    p1 += v * W3[2 * c + 1];
    r0 += v * Wres2[2 * c]; r1 += v * Wres2[2 * c + 1];
  }
  float s0 = 0.f, s1 = 0.f;
  const float* xr = x + (size_t)n * FIN;
  for (int c = lane; c < FIN; c += 64) {
    float v = xr[c];
    s0 += v * Wskip[2 * c]; s1 += v * Wskip[2 * c + 1];
  }
#pragma unroll
  for (int off = 32; off; off >>= 1) {
    p0 += __shfl_down(p0, off); p1 += __shfl_down(p1, off);
    r0 += __shfl_down(r0, off); r1 += __shfl_down(r1, off);
    s0 += __shfl_down(s0, off); s1 += __shfl_down(s1, off);
  }
  if (!lane) {
    H3p[2 * n] = p0; H3p[2 * n + 1] = p1;
    es3[n] = p0 * a3s[0] + p1 * a3s[1];
    ed3[n] = p0 * a3d[0] + p1 * a3d[1];
    base[2 * n]     = r0 + s0 + b3[0];
    base[2 * n + 1] = r1 + s1 + b3[1];
  }
}

// ---------------- layer 3 softmax+aggregate (1 head, 2 ch) -> final logits ----------------
__global__ void k_l3agg(const int* __restrict__ rs, const int* __restrict__ esrc,
                        const float* __restrict__ H3p, const float* __restrict__ base,
                        const float* __restrict__ es3, const float* __restrict__ ed3,
                        float* __restrict__ out) {
  int n = blockIdx.x * 256 + threadIdx.x;
  if (n >= NN) return;
  int beg = rs[n], end = rs[n + 1];
  float edv = ed3[n];
  float m = -3e38f;
  for (int j = beg; j < end; ++j) {
    float e = es3[esrc[j]] + edv;
    e = e > 0.f ? e : NEG * e;
    m = fmaxf(m, e);
  }
  float den = 0.f, a0 = 0.f, a1 = 0.f;
  for (int j = beg; j < end; ++j) {
    int s = esrc[j];
    float e = es3[s] + edv;
    e = e > 0.f ? e : NEG * e;
    float exv = __expf(e - m);
    den += exv;
    a0 += exv * H3p[2 * s];
    a1 += exv * H3p[2 * s + 1];
  }
  float inv = 1.f / (den + 1e-16f);
  out[2 * n]     = base[2 * n]     + a0 * inv;
  out[2 * n + 1] = base[2 * n + 1] + a1 * inv;
}

extern "C" void kernel_launch(void* const* d_in, const int* in_sizes, int n_in,
                              void* d_out, int out_size, void* d_ws, size_t ws_size,
                              hipStream_t stream) {
  (void)in_sizes; (void)n_in; (void)out_size; (void)ws_size;
  const float* x    = (const float*)d_in[0];
  const int*   ei   = (const int*)d_in[1];
  const float* W1   = (const float*)d_in[2];
  const float* a1s  = (const float*)d_in[3];
  const float* a1d  = (const float*)d_in[4];
  const float* b1   = (const float*)d_in[5];
  const float* W2   = (const float*)d_in[6];
  const float* a2s  = (const float*)d_in[7];
  const float* a2d  = (const float*)d_in[8];
  const float* b2   = (const float*)d_in[9];
  const float* W3   = (const float*)d_in[10];
  const float* a3s  = (const float*)d_in[11];
  const float* a3d  = (const float*)d_in[12];
  const float* b3   = (const float*)d_in[13];
  const float* Wr1  = (const float*)d_in[14];
  const float* Wr2  = (const float*)d_in[15];
  const float* Wsk  = (const float*)d_in[16];
  float* out = (float*)d_out;

  char* w = (char*)d_ws;
  size_t off = 0;
  auto alloc = [&](size_t bytes) { void* p = w + off; off += (bytes + 255) & ~(size_t)255; return p; };
  int* cnt   = (int*)alloc((size_t)NN * 4);
  int* cur   = (int*)alloc((size_t)NN * 4);
  int* rs    = (int*)alloc((size_t)(NN + 1) * 4);
  int* bs    = (int*)alloc(256 * 4);
  int* esrc  = (int*)alloc((size_t)ETOT * 4);
  float* es  = (float*)alloc((size_t)NN * HEADS * 4);
  float* ed  = (float*)alloc((size_t)NN * HEADS * 4);
  float* exb = (float*)alloc((size_t)ETOT * HEADS * 4);
  float* dvf = (float*)alloc((size_t)NN * HEADS * 4);
  u16* W1t   = (u16*)alloc((size_t)NP1 * KP1 * 2);
  u16* W2t   = (u16*)alloc((size_t)NP2 * DIM * 2);
  float* H3p = (float*)alloc((size_t)NN * 2 * 4);
  float* base= (float*)alloc((size_t)NN * 2 * 4);
  float* es3 = (float*)alloc((size_t)NN * 4);
  float* ed3 = (float*)alloc((size_t)NN * 4);
  u16* bufB  = (u16*)alloc((size_t)MPAD * DIM * 2);    // h1bf, later h2bf
  u16* bufA  = (u16*)alloc((size_t)MPAD * DIM2 * 2);   // H1p, later G2 (fused proj|resid)
  u16* H1p   = bufA;
  u16* G2    = bufA;
  u16* A1    = bufA + (size_t)MPAD * DIM;              // alias upper half of bufA (dead before G2)

  const int nb = (NN + 255) / 256;        // 196
  const int ge = (ETOT + 255) / 256;      // 977
  const int gh = (NN * HEADS + 255) / 256;// 1563

  // CSR build
  hipMemsetAsync(cnt, 0, (size_t)NN * 4, stream);
  hipMemsetAsync(cur, 0, (size_t)NN * 4, stream);
  k_count<<<ge, 256, 0, stream>>>(ei, cnt);
  k_bsum <<<nb, 256, 0, stream>>>(cnt, bs);
  k_top  <<<1, 256, 0, stream>>>(bs, rs, nb);
  k_scan <<<nb, 256, 0, stream>>>(cnt, bs, rs);
  k_fill <<<ge, 256, 0, stream>>>(ei, rs, cur, esrc);

  // converts
  k_cvt_x <<<(MPAD * KP1) / 256, 256, 0, stream>>>(x, A1);
  k_cvt_w1<<<(NP1 * KP1) / 256, 256, 0, stream>>>(W1, W1t);
  k_cvt_w2<<<(NP2 * DIM) / 256, 256, 0, stream>>>(W2, Wr1, W2t);

  // layer 1
  k_gemm<<<dim3(NP1 / 128, MPAD / 128), 256, 0, stream>>>(A1, W1t, H1p, KP1 / 32, KP1, DIM, DIM);
  k_esed <<<gh, 256, 0, stream>>>(H1p, DIM, a1s, a1d, es, ed);
  k_stats<<<gh, 256, 0, stream>>>(rs, esrc, es, ed, exb, dvf);
  k_agg<1><<<NN, 256, 0, stream>>>(rs, esrc, H1p, exb, dvf, b1, (const u16*)nullptr, bufB);

  // layer 2 (W2 and Wres1 fused into one GEMM: cols [0,800)=proj, [800,1600)=residual)
  k_gemm<<<dim3(NP2 / 128, MPAD / 128), 256, 0, stream>>>(bufB, W2t, G2, DIM / 32, DIM, DIM2, DIM2);
  k_esed <<<gh, 256, 0, stream>>>(G2, DIM2, a2s, a2d, es, ed);
  k_stats<<<gh, 256, 0, stream>>>(rs, esrc, es, ed, exb, dvf);
  k_agg<2><<<NN, 256, 0, stream>>>(rs, esrc, G2, exb, dvf, b2, G2 + DIM, bufB);

  // layer 3
  k_l3   <<<(NN + 3) / 4, 256, 0, stream>>>(bufB, x, W3, Wr2, Wsk, a3s, a3d, b3, H3p, base, es3, ed3);
  k_l3agg<<<nb, 256, 0, stream>>>(rs, esrc, H3p, base, es3, ed3, out);
}

// Round 4
// 558.465 us; speedup vs baseline: 1.4128x; 1.1501x over previous
//
#include <hip/hip_runtime.h>

#define NN     50000
#define NE     200000
#define ETOT   250000   // NE + NN self-loops
#define FIN    165
#define KP1    192      // FIN padded to mult of 32
#define HEADS  8
#define CH     100
#define DIM    800      // 8*100
#define MPAD   50048    // 391*128
#define NP1    896      // 7*128  (pad of 800; cols 800-815 = fused es/ed)
#define DIM2   1600     // W2|Wres1 fused output
#define NP2    1664     // 13*128 (pad of 1600; cols 1600-1615 = fused es/ed)
#define NEG    0.2f

typedef unsigned short u16;
typedef unsigned int   u32;
typedef __bf16 bf16x8 __attribute__((ext_vector_type(8)));
typedef float  f32x4  __attribute__((ext_vector_type(4)));

__device__ __forceinline__ u16 f2b(float f) {
  u32 u = __float_as_uint(f);
  u = (u + 0x7FFFu + ((u >> 16) & 1u)) >> 16;   // RNE
  return (u16)u;
}
__device__ __forceinline__ float b2f(u16 u) { return __uint_as_float(((u32)u) << 16); }

// ---------------- CSR build (dst -> list of src), reused by all 3 layers ----------------
__global__ void k_count(const int* __restrict__ ei, int* __restrict__ cnt) {
  int e = blockIdx.x * 256 + threadIdx.x;
  if (e >= ETOT) return;
  int d = (e < NE) ? ei[NE + e] : (e - NE);
  atomicAdd(&cnt[d], 1);
}
__global__ void k_bsum(const int* __restrict__ cnt, int* __restrict__ bs) {
  __shared__ int sm[256];
  int i = blockIdx.x * 256 + threadIdx.x;
  sm[threadIdx.x] = (i < NN) ? cnt[i] : 0;
  __syncthreads();
  for (int off = 128; off; off >>= 1) {
    if (threadIdx.x < off) sm[threadIdx.x] += sm[threadIdx.x + off];
    __syncthreads();
  }
  if (!threadIdx.x) bs[blockIdx.x] = sm[0];
}
__global__ void k_top(int* __restrict__ bs, int* __restrict__ rs, int nb) {
  __shared__ int sm[256];
  int t = threadIdx.x;
  int v = (t < nb) ? bs[t] : 0;
  sm[t] = v; __syncthreads();
  for (int off = 1; off < 256; off <<= 1) {
    int add = (t >= off) ? sm[t - off] : 0;
    __syncthreads();
    sm[t] += add;
    __syncthreads();
  }
  if (t < nb) bs[t] = sm[t] - v;   // exclusive block offsets
  if (!t) rs[NN] = ETOT;
}
__global__ void k_scan(const int* __restrict__ cnt, const int* __restrict__ bs, int* __restrict__ rs) {
  __shared__ int sm[256];
  int t = threadIdx.x, i = blockIdx.x * 256 + t;
  int v = (i < NN) ? cnt[i] : 0;
  sm[t] = v; __syncthreads();
  for (int off = 1; off < 256; off <<= 1) {
    int add = (t >= off) ? sm[t - off] : 0;
    __syncthreads();
    sm[t] += add;
    __syncthreads();
  }
  if (i < NN) rs[i] = bs[blockIdx.x] + sm[t] - v;
}
__global__ void k_fill(const int* __restrict__ ei, const int* __restrict__ rs,
                       int* __restrict__ cur, int* __restrict__ esrc) {
  int e = blockIdx.x * 256 + threadIdx.x;
  if (e >= ETOT) return;
  int s, d;
  if (e < NE) { s = ei[e]; d = ei[NE + e]; } else { s = d = e - NE; }
  int pos = atomicAdd(&cur[d], 1);
  esrc[rs[d] + pos] = s;
}

// ---------------- converts (fp32 -> bf16, pad, transpose weights) ----------------
__global__ void k_cvt_x(const float* __restrict__ x, u16* __restrict__ A) {
  int idx = blockIdx.x * 256 + threadIdx.x;   // MPAD*KP1 exact
  int r = idx / KP1, k = idx - r * KP1;
  float v = (r < NN && k < FIN) ? x[r * FIN + k] : 0.f;
  A[idx] = f2b(v);
}
__global__ void k_cvt_w1(const float* __restrict__ W1, u16* __restrict__ Bt) {
  int idx = blockIdx.x * 256 + threadIdx.x;   // NP1*KP1 exact
  int j = idx / KP1, k = idx - j * KP1;
  float v = (j < DIM && k < FIN) ? W1[k * DIM + j] : 0.f;
  Bt[idx] = f2b(v);
}
__global__ void k_cvt_w2(const float* __restrict__ W2, const float* __restrict__ Wr1,
                         u16* __restrict__ Bt) {
  int idx = blockIdx.x * 256 + threadIdx.x;   // NP2*DIM exact
  int j = idx / DIM, k = idx - j * DIM;
  float v = 0.f;
  if (j < DIM) v = W2[k * DIM + j];
  else if (j < 2 * DIM) v = Wr1[k * DIM + (j - DIM)];
  Bt[idx] = f2b(v);
}
// fused attention columns: Wt row (Dsp+j), j=h -> (W @ a_src blockdiag), j=8+h -> a_dst.
// es = (x@W)@a == x@(W@a) by associativity; rides along in the main GEMM for free.
__global__ void k_wa(const float* __restrict__ W, const float* __restrict__ as,
                     const float* __restrict__ ad, u16* __restrict__ Wt,
                     int Kin, int Kpad, int Dsp) {
  int idx = blockIdx.x * 256 + threadIdx.x;
  if (idx >= 16 * Kpad) return;
  int j = idx / Kpad, k = idx - j * Kpad;
  int h = j & 7;
  const float* a = ((j < 8) ? as : ad) + h * CH;
  float s = 0.f;
  if (k < Kin) {
    const float* wr = W + (size_t)k * DIM + h * CH;
    for (int c = 0; c < CH; ++c) s += wr[c] * a[c];
  }
  Wt[(size_t)(Dsp + j) * Kpad + k] = f2b(s);
}

// ---------------- bf16 MFMA GEMM: C[M][ldC] = A[M][K] * Bt[Npad][K]^T ----------------
// T1: bijective XCD-chunked block swizzle (m204) -> A-panel reuse in one XCD's L2.
// T3-minimal: double-buffered LDS, STAGE(next) issued before ds_read+MFMA of current,
// ONE barrier per K-step (compiler's vmcnt(0)-drain at barrier provides the wait).
// Cols >= Dsplit are the fused es/ed columns, written as f32 to separate buffers.
__device__ __forceinline__ void gl_lds16(const u16* g, u16* l) {
  __builtin_amdgcn_global_load_lds((const __attribute__((address_space(1))) void*)g,
                                   (__attribute__((address_space(3))) void*)l, 16, 0, 0);
}

__global__ __launch_bounds__(256) void k_gemm(const u16* __restrict__ A, const u16* __restrict__ Bt,
                                              u16* __restrict__ C, float* __restrict__ es,
                                              float* __restrict__ ed, int ksteps, int K,
                                              int Dsplit, int Nreal, int ldC) {
  __shared__ __align__(16) u16 lA[2][128 * 32];
  __shared__ __align__(16) u16 lB[2][128 * 32];
  int t = threadIdx.x;
  int lane = t & 63, wv = t >> 6;

  // T1 XCD swizzle (hardware id -> logical tile id, bijective chunked)
  int nwg = gridDim.x * gridDim.y;
  int h = blockIdx.y * gridDim.x + blockIdx.x;
  int q = nwg >> 3, r8 = nwg & 7;
  int xcd = h & 7, i8 = h >> 3;
  int ln = (xcd < r8 ? xcd * (q + 1) : r8 * (q + 1) + (xcd - r8) * q) + i8;
  int tn = (ln % gridDim.x) * 128, tm = (ln / gridDim.x) * 128;

  int wr = (wv >> 1) * 64, wc = (wv & 1) * 64;
  int rl = lane & 15, kl = (lane >> 4) * 8;
  int srow = t >> 2, scb = (t & 3) * 8;      // staging: thread -> (row, col-block)

  f32x4 acc[4][4];
#pragma unroll
  for (int i = 0; i < 4; ++i)
#pragma unroll
    for (int j = 0; j < 4; ++j) acc[i][j] = (f32x4){0.f, 0.f, 0.f, 0.f};

  auto stage = [&](int buf, int ks) {
    int k0 = ks * 32;
#pragma unroll
    for (int r = 0; r < 2; ++r) {
      int row = srow + r * 64;
      int chunk = (r * 256 + t) * 8;
      gl_lds16(A + (size_t)(tm + row) * K + k0 + scb, &lA[buf][chunk]);
      gl_lds16(Bt + (size_t)(tn + row) * K + k0 + scb, &lB[buf][chunk]);
    }
  };

  stage(0, 0);
  int cur = 0;
  for (int ks = 0; ks < ksteps; ++ks) {
    __syncthreads();                       // drains vmcnt(0): buf[cur] fully written
    if (ks + 1 < ksteps) stage(cur ^ 1, ks + 1);   // loads fly under the MFMAs below
    bf16x8 af[4], bfr[4];
#pragma unroll
    for (int i = 0; i < 4; ++i) {
      af[i]  = *(const bf16x8*)&lA[cur][(wr + i * 16 + rl) * 32 + kl];
      bfr[i] = *(const bf16x8*)&lB[cur][(wc + i * 16 + rl) * 32 + kl];
    }
#pragma unroll
    for (int i = 0; i < 4; ++i)
#pragma unroll
      for (int j = 0; j < 4; ++j)
        acc[i][j] = __builtin_amdgcn_mfma_f32_16x16x32_bf16(af[i], bfr[j], acc[i][j], 0, 0, 0);
    cur ^= 1;
  }
  int rq = (lane >> 4) * 4;
#pragma unroll
  for (int i = 0; i < 4; ++i) {
#pragma unroll
    for (int j = 0; j < 4; ++j) {
      int col = tn + wc + j * 16 + rl;
      if (col < Dsplit) {
#pragma unroll
        for (int q2 = 0; q2 < 4; ++q2) {
          int row = tm + wr + i * 16 + rq + q2;
          C[(size_t)row * ldC + col] = f2b(acc[i][j][q2]);
        }
      } else if (col < Nreal) {
        int cj = col - Dsplit;
        float* dst = (cj < 8) ? es : ed;
        int hh = cj & 7;
#pragma unroll
        for (int q2 = 0; q2 < 4; ++q2) {
          int row = tm + wr + i * 16 + rq + q2;
          dst[(size_t)row * 8 + hh] = acc[i][j][q2];
        }
      }
    }
  }
}

// ---- per-(node,head) softmax stats; single pass (shift-invariant, m=0), stores exp ----
__global__ void k_stats(const int* __restrict__ rs, const int* __restrict__ esrc,
                        const float* __restrict__ es, const float* __restrict__ ed,
                        float* __restrict__ ex, float* __restrict__ dv) {
  int idx = blockIdx.x * 256 + threadIdx.x;
  if (idx >= NN * HEADS) return;
  int n = idx >> 3, h = idx & 7;
  int beg = rs[n], end = rs[n + 1];
  float edv = ed[idx];
  float den = 0.f;
  for (int j = beg; j < end; ++j) {
    float x = es[esrc[j] * 8 + h] + edv;
    x = x > 0.f ? x : NEG * x;
    float e = __expf(x);
    ex[j * 8 + h] = e;
    den += e;
  }
  dv[idx] = 1.f / (den + 1e-16f);
}

// ---- aggregation: hot loop is ex-broadcast + ushort4 gather + FMA only ----
template <int LAYER>
__global__ __launch_bounds__(256) void k_agg(const int* __restrict__ rs, const int* __restrict__ esrc,
    const u16* __restrict__ Hp, const float* __restrict__ ex, const float* __restrict__ dv,
    const float* __restrict__ bias, const u16* __restrict__ resid, u16* __restrict__ out) {
  const int ld = (LAYER == 2) ? DIM2 : DIM;
  int n = blockIdx.x, t = threadIdx.x;
  if (t >= 200) return;
  int beg = rs[n], end = rs[n + 1];
  int c = t * 4;
  int h = t / 25;
  float inv = dv[n * 8 + h];
  float a0 = 0.f, a1 = 0.f, a2 = 0.f, a3 = 0.f;
  for (int j = beg; j < end; ++j) {
    int s = esrc[j];
    float w = ex[j * 8 + h];
    ushort4 u = *(const ushort4*)(Hp + (size_t)s * ld + c);
    a0 += w * b2f(u.x); a1 += w * b2f(u.y); a2 += w * b2f(u.z); a3 += w * b2f(u.w);
  }
  const float4 bb = *(const float4*)(bias + c);
  float v0 = a0 * inv + bb.x, v1 = a1 * inv + bb.y, v2 = a2 * inv + bb.z, v3 = a3 * inv + bb.w;
  if (LAYER == 2) {
    ushort4 r = *(const ushort4*)(resid + (size_t)n * DIM2 + c);
    v0 += b2f(r.x); v1 += b2f(r.y); v2 += b2f(r.z); v3 += b2f(r.w);
  }
  v0 = v0 > 0.f ? v0 : __expf(v0) - 1.f;
  v1 = v1 > 0.f ? v1 : __expf(v1) - 1.f;
  v2 = v2 > 0.f ? v2 : __expf(v2) - 1.f;
  v3 = v3 > 0.f ? v3 : __expf(v3) - 1.f;
  ushort4 o;
  o.x = f2b(v0); o.y = f2b(v1); o.z = f2b(v2); o.w = f2b(v3);
  *(ushort4*)(out + (size_t)n * DIM + c) = o;
}

// ---------------- layer 3: skinny projections, one wave per node ----------------
__global__ __launch_bounds__(256) void k_l3(const u16* __restrict__ h2, const float* __restrict__ x,
    const float* __restrict__ W3, const float* __restrict__ Wres2, const float* __restrict__ Wskip,
    const float* __restrict__ a3s, const float* __restrict__ a3d, const float* __restrict__ b3,
    float* __restrict__ H3p, float* __restrict__ base, float* __restrict__ es3, float* __restrict__ ed3) {
  int wv = threadIdx.x >> 6, lane = threadIdx.x & 63;
  int n = blockIdx.x * 4 + wv;
  if (n >= NN) return;
  float p0 = 0.f, p1 = 0.f, r0 = 0.f, r1 = 0.f;
  const u16* hr = h2 + (size_t)n * DIM;
  for (int c = lane; c < DIM; c += 64) {
    float v = b2f(hr[c]);
    p0 += v * W3[2 * c];    p1 += v * W3[2 * c + 1];
    r0 += v * Wres2[2 * c]; r1 += v * Wres2[2 * c + 1];
  }
  float s0 = 0.f, s1 = 0.f;
  const float* xr = x + (size_t)n * FIN;
  for (int c = lane; c < FIN; c += 64) {
    float v = xr[c];
    s0 += v * Wskip[2 * c]; s1 += v * Wskip[2 * c + 1];
  }
#pragma unroll
  for (int off = 32; off; off >>= 1) {
    p0 += __shfl_down(p0, off); p1 += __shfl_down(p1, off);
    r0 += __shfl_down(r0, off); r1 += __shfl_down(r1, off);
    s0 += __shfl_down(s0, off); s1 += __shfl_down(s1, off);
  }
  if (!lane) {
    H3p[2 * n] = p0; H3p[2 * n + 1] = p1;
    es3[n] = p0 * a3s[0] + p1 * a3s[1];
    ed3[n] = p0 * a3d[0] + p1 * a3d[1];
    base[2 * n]     = r0 + s0 + b3[0];
    base[2 * n + 1] = r1 + s1 + b3[1];
  }
}

// ---------------- layer 3 softmax+aggregate (1 head, 2 ch) -> final logits ----------------
__global__ void k_l3agg(const int* __restrict__ rs, const int* __restrict__ esrc,
                        const float* __restrict__ H3p, const float* __restrict__ base,
                        const float* __restrict__ es3, const float* __restrict__ ed3,
                        float* __restrict__ out) {
  int n = blockIdx.x * 256 + threadIdx.x;
  if (n >= NN) return;
  int beg = rs[n], end = rs[n + 1];
  float edv = ed3[n];
  float den = 0.f, a0 = 0.f, a1 = 0.f;
  for (int j = beg; j < end; ++j) {
    int s = esrc[j];
    float e = es3[s] + edv;
    e = e > 0.f ? e : NEG * e;
    float exv = __expf(e);
    den += exv;
    a0 += exv * H3p[2 * s];
    a1 += exv * H3p[2 * s + 1];
  }
  float inv = 1.f / (den + 1e-16f);
  out[2 * n]     = base[2 * n]     + a0 * inv;
  out[2 * n + 1] = base[2 * n + 1] + a1 * inv;
}

extern "C" void kernel_launch(void* const* d_in, const int* in_sizes, int n_in,
                              void* d_out, int out_size, void* d_ws, size_t ws_size,
                              hipStream_t stream) {
  (void)in_sizes; (void)n_in; (void)out_size; (void)ws_size;
  const float* x    = (const float*)d_in[0];
  const int*   ei   = (const int*)d_in[1];
  const float* W1   = (const float*)d_in[2];
  const float* a1s  = (const float*)d_in[3];
  const float* a1d  = (const float*)d_in[4];
  const float* b1   = (const float*)d_in[5];
  const float* W2   = (const float*)d_in[6];
  const float* a2s  = (const float*)d_in[7];
  const float* a2d  = (const float*)d_in[8];
  const float* b2   = (const float*)d_in[9];
  const float* W3   = (const float*)d_in[10];
  const float* a3s  = (const float*)d_in[11];
  const float* a3d  = (const float*)d_in[12];
  const float* b3   = (const float*)d_in[13];
  const float* Wr1  = (const float*)d_in[14];
  const float* Wr2  = (const float*)d_in[15];
  const float* Wsk  = (const float*)d_in[16];
  float* out = (float*)d_out;

  char* w = (char*)d_ws;
  size_t off = 0;
  auto alloc = [&](size_t bytes) { void* p = w + off; off += (bytes + 255) & ~(size_t)255; return p; };
  int* cnt   = (int*)alloc((size_t)NN * 4);
  int* cur   = (int*)alloc((size_t)NN * 4);
  int* rs    = (int*)alloc((size_t)(NN + 1) * 4);
  int* bs    = (int*)alloc(256 * 4);
  int* esrc  = (int*)alloc((size_t)ETOT * 4);
  float* es  = (float*)alloc((size_t)MPAD * HEADS * 4);
  float* ed  = (float*)alloc((size_t)MPAD * HEADS * 4);
  float* exb = (float*)alloc((size_t)ETOT * HEADS * 4);
  float* dvf = (float*)alloc((size_t)NN * HEADS * 4);
  u16* W1t   = (u16*)alloc((size_t)NP1 * KP1 * 2);
  u16* W2t   = (u16*)alloc((size_t)NP2 * DIM * 2);
  float* H3p = (float*)alloc((size_t)NN * 2 * 4);
  float* base= (float*)alloc((size_t)NN * 2 * 4);
  float* es3 = (float*)alloc((size_t)NN * 4);
  float* ed3 = (float*)alloc((size_t)NN * 4);
  u16* bufB  = (u16*)alloc((size_t)MPAD * DIM * 2);    // h1bf, later h2bf
  u16* bufA  = (u16*)alloc((size_t)MPAD * DIM2 * 2);   // H1p, later G2 (fused proj|resid)
  u16* H1p   = bufA;
  u16* G2    = bufA;
  u16* A1    = bufA + (size_t)MPAD * DIM;              // alias upper half of bufA (dead before G2)

  const int nb = (NN + 255) / 256;        // 196
  const int ge = (ETOT + 255) / 256;      // 977
  const int gh = (NN * HEADS + 255) / 256;// 1563

  // CSR build
  hipMemsetAsync(cnt, 0, (size_t)NN * 4, stream);
  hipMemsetAsync(cur, 0, (size_t)NN * 4, stream);
  k_count<<<ge, 256, 0, stream>>>(ei, cnt);
  k_bsum <<<nb, 256, 0, stream>>>(cnt, bs);
  k_top  <<<1, 256, 0, stream>>>(bs, rs, nb);
  k_scan <<<nb, 256, 0, stream>>>(cnt, bs, rs);
  k_fill <<<ge, 256, 0, stream>>>(ei, rs, cur, esrc);

  // converts (+ fused es/ed weight columns)
  k_cvt_x <<<(MPAD * KP1) / 256, 256, 0, stream>>>(x, A1);
  k_cvt_w1<<<(NP1 * KP1) / 256, 256, 0, stream>>>(W1, W1t);
  k_wa    <<<(16 * KP1 + 255) / 256, 256, 0, stream>>>(W1, a1s, a1d, W1t, FIN, KP1, DIM);
  k_cvt_w2<<<(NP2 * DIM) / 256, 256, 0, stream>>>(W2, Wr1, W2t);
  k_wa    <<<(16 * DIM + 255) / 256, 256, 0, stream>>>(W2, a2s, a2d, W2t, DIM, DIM, DIM2);

  // layer 1 (GEMM also emits es/ed via fused columns 800-815)
  k_gemm<<<dim3(NP1 / 128, MPAD / 128), 256, 0, stream>>>(A1, W1t, H1p, es, ed,
                                                          KP1 / 32, KP1, DIM, DIM + 16, DIM);
  k_stats<<<gh, 256, 0, stream>>>(rs, esrc, es, ed, exb, dvf);
  k_agg<1><<<NN, 256, 0, stream>>>(rs, esrc, H1p, exb, dvf, b1, (const u16*)nullptr, bufB);

  // layer 2 (W2|Wres1 fused GEMM; es/ed via fused columns 1600-1615)
  k_gemm<<<dim3(NP2 / 128, MPAD / 128), 256, 0, stream>>>(bufB, W2t, G2, es, ed,
                                                          DIM / 32, DIM, DIM2, DIM2 + 16, DIM2);
  k_stats<<<gh, 256, 0, stream>>>(rs, esrc, es, ed, exb, dvf);
  k_agg<2><<<NN, 256, 0, stream>>>(rs, esrc, G2, exb, dvf, b2, G2 + DIM, bufB);

  // layer 3
  k_l3   <<<(NN + 3) / 4, 256, 0, stream>>>(bufB, x, W3, Wr2, Wsk, a3s, a3d, b3, H3p, base, es3, ed3);
  k_l3agg<<<nb, 256, 0, stream>>>(rs, esrc, H3p, base, es3, ed3, out);
}